// Round 1
// 64.612 us; speedup vs baseline: 1.0376x; 1.0376x over previous
//
#include <hip/hip_runtime.h>

#define K_MODES 128
#define TABLE_M 4096   // table resolution over t in [0,1); 32 KB table

// ---------- Kernel A: build f(j/M), 2 lanes per point (split-K via shuffle) ----
__global__ __launch_bounds__(256) void build_table_kernel(
    const float* __restrict__ params,   // [3, K] : Gamma, omega, gamma
    float2* __restrict__ table)         // [TABLE_M + 1] (re, im)
{
    __shared__ float sG[K_MODES];
    __shared__ float sW[K_MODES];   // omega / (2*pi)   (v_sin takes revolutions)
    __shared__ float sE[K_MODES];   // -gamma * log2(e) (v_exp computes 2^x)

    const int tid = threadIdx.x;
    if (tid < K_MODES) {
        sG[tid] = params[tid];
        sW[tid] = params[K_MODES + tid]     * 0.15915494309189535f;
        sE[tid] = params[2 * K_MODES + tid] * (-1.4426950408889634f);
    }
    __syncthreads();

    const int g = blockIdx.x * blockDim.x + tid;
    const int j = g >> 1;            // table point
    const int h = g & 1;             // K-half handled by this lane
    if (j > TABLE_M) return;

    const float t  = (float)j * (1.0f / TABLE_M);
    const int   k0 = h * (K_MODES / 2);
    float re = 0.0f, im = 0.0f;

#pragma unroll 8
    for (int k = k0; k < k0 + K_MODES / 2; ++k) {
        const float r  = sW[k] * t;
        const float s  = __builtin_amdgcn_sinf(r);
        const float c  = __builtin_amdgcn_cosf(r);
        const float e  = __builtin_amdgcn_exp2f(sE[k] * t);
        const float ge = sG[k] * e;
        re = fmaf(ge, c, re);
        im = fmaf(ge, s, im);
    }

    // combine the two K-halves (adjacent lanes)
    re += __shfl_xor(re, 1);
    im += __shfl_xor(im, 1);
    if (h == 0) table[j] = make_float2(re, im);
}

// ---------- Kernel B: LDS-staged table, linear interp, 4 points/thread --------
// Random per-lane table gathers move from L1 (line-granular: up to 64 serialized
// cache-line touches per diverged wave gather) to LDS (bank-granular: ~4-way
// conflicts on random b64 addresses ~= 1.6x base). Table is 32.8 KB LDS;
// 4 blocks/CU co-resident (131 KB of 160 KB).
__global__ __launch_bounds__(256) void interp_lds_kernel(
    const float* __restrict__ tg,       // [T], values in [0,1)
    const float2* __restrict__ table,   // [TABLE_M + 1] in global (from kernel A)
    float* __restrict__ out,            // planar: [0..T-1]=re, [T..2T-1]=im
    int T,
    int out_floats)
{
    __shared__ __align__(16) float2 sTab[TABLE_M + 1];

    const int tid = threadIdx.x;

    // Cooperative stage: 4096 entries as 2048 float4 (coalesced, L2-resident
    // source), plus the final guard entry.
    {
        const float4* __restrict__ src4 = (const float4*)table;
        float4* dst4 = (float4*)sTab;
#pragma unroll
        for (int j = tid; j < (TABLE_M * 2) / 4; j += 256)   // 2048 float4
            dst4[j] = src4[j];
        if (tid == 0) sTab[TABLE_M] = table[TABLE_M];
    }
    __syncthreads();

    const int i4 = blockIdx.x * blockDim.x + tid;  // group of 4
    const int i  = i4 * 4;
    if (i >= T) return;

    float4 re4, im4;

    if (i + 3 < T && (T + i + 3) < out_floats) {
        const float4 t4 = *(const float4*)(tg + i);
        const float* tv = (const float*)&t4;
        float* rp = (float*)&re4;
        float* ip = (float*)&im4;
#pragma unroll
        for (int c = 0; c < 4; ++c) {
            float u = tv[c] * (float)TABLE_M;
            u = fminf(fmaxf(u, 0.0f), (float)TABLE_M - 0.0001f);
            const int   idx = (int)u;
            const float f   = u - (float)idx;
            const float2 a = sTab[idx];
            const float2 b = sTab[idx + 1];
            rp[c] = fmaf(b.x - a.x, f, a.x);
            ip[c] = fmaf(b.y - a.y, f, a.y);
        }
        *(float4*)(out + i)     = re4;
        *(float4*)(out + T + i) = im4;
    } else {
        // tail / defensive scalar path
        for (int c = 0; c < 4 && i + c < T; ++c) {
            float u = tg[i + c] * (float)TABLE_M;
            u = fminf(fmaxf(u, 0.0f), (float)TABLE_M - 0.0001f);
            const int   idx = (int)u;
            const float f   = u - (float)idx;
            const float2 a = sTab[idx];
            const float2 b = sTab[idx + 1];
            if (i + c < out_floats)     out[i + c]     = fmaf(b.x - a.x, f, a.x);
            if (T + i + c < out_floats) out[T + i + c] = fmaf(b.y - a.y, f, a.y);
        }
    }
}

// ---------- Fallback: proven direct kernel (R4) if d_ws is too small ----------
__global__ __launch_bounds__(256) void propag_direct_kernel(
    const float* __restrict__ params,
    const float* __restrict__ tg,
    float* __restrict__ out,
    int T,
    int out_floats)
{
    __shared__ float sG[K_MODES];
    __shared__ float sW[K_MODES];
    __shared__ float sE[K_MODES];

    const int tid = threadIdx.x;
    if (tid < K_MODES) {
        sG[tid] = params[tid];
        sW[tid] = params[K_MODES + tid]     * 0.15915494309189535f;
        sE[tid] = params[2 * K_MODES + tid] * (-1.4426950408889634f);
    }
    __syncthreads();

    const int i = blockIdx.x * blockDim.x + tid;
    if (i >= T) return;

    const float t = tg[i];
    float re = 0.0f, im = 0.0f;

#pragma unroll 8
    for (int k = 0; k < K_MODES; ++k) {
        const float r  = sW[k] * t;
        const float s  = __builtin_amdgcn_sinf(r);
        const float c  = __builtin_amdgcn_cosf(r);
        const float e  = __builtin_amdgcn_exp2f(sE[k] * t);
        const float ge = sG[k] * e;
        re = fmaf(ge, c, re);
        im = fmaf(ge, s, im);
    }

    if (i < out_floats)     out[i]     = re;
    if (T + i < out_floats) out[T + i] = im;
}

extern "C" void kernel_launch(void* const* d_in, const int* in_sizes, int n_in,
                              void* d_out, int out_size, void* d_ws, size_t ws_size,
                              hipStream_t stream) {
    // Resolve inputs by element count: parameters has exactly 3*128 = 384.
    int ip = 0, it = 1;
    if (in_sizes[0] != 3 * K_MODES) { ip = 1; it = 0; }
    const float* params = (const float*)d_in[ip];
    const float* tg     = (const float*)d_in[it];
    float* out          = (float*)d_out;
    const int T = in_sizes[it];

    const size_t table_bytes = (size_t)(TABLE_M + 1) * sizeof(float2);
    const int block = 256;

    if (ws_size >= table_bytes && d_ws != nullptr) {
        float2* table = (float2*)d_ws;
        const int nthreadA = 2 * (TABLE_M + 1);           // 2 lanes per point
        const int gridA = (nthreadA + block - 1) / block;
        build_table_kernel<<<gridA, block, 0, stream>>>(params, table);

        const int n4 = (T + 3) / 4;
        const int gridB = (n4 + block - 1) / block;
        interp_lds_kernel<<<gridB, block, 0, stream>>>(tg, table, out, T, out_size);
    } else {
        const int grid = (T + block - 1) / block;
        propag_direct_kernel<<<grid, block, 0, stream>>>(params, tg, out, T, out_size);
    }
}

// Round 2
// 64.033 us; speedup vs baseline: 1.0470x; 1.0091x over previous
//
#include <hip/hip_runtime.h>

#define K_MODES 128
#define TABLE_M 4096   // table resolution over t in [0,1); 32 KB table

// ---- async global->LDS copy, 16B per lane (dest = wave-uniform base + lane*16)
typedef const __attribute__((address_space(1))) void g_void_t;
typedef __attribute__((address_space(3))) void l_void_t;
__device__ __forceinline__ void async_copy16(const void* g, void* l) {
    __builtin_amdgcn_global_load_lds((g_void_t*)g, (l_void_t*)l, 16, 0, 0);
}

// ---------- Kernel A: build f(j/M), 2 lanes per point (split-K via shuffle) ----
__global__ __launch_bounds__(256) void build_table_kernel(
    const float* __restrict__ params,   // [3, K] : Gamma, omega, gamma
    float2* __restrict__ table)         // [TABLE_M + 1] (re, im)
{
    __shared__ float sG[K_MODES];
    __shared__ float sW[K_MODES];   // omega / (2*pi)   (v_sin takes revolutions)
    __shared__ float sE[K_MODES];   // -gamma * log2(e) (v_exp computes 2^x)

    const int tid = threadIdx.x;
    if (tid < K_MODES) {
        sG[tid] = params[tid];
        sW[tid] = params[K_MODES + tid]     * 0.15915494309189535f;
        sE[tid] = params[2 * K_MODES + tid] * (-1.4426950408889634f);
    }
    __syncthreads();

    const int g = blockIdx.x * blockDim.x + tid;
    const int j = g >> 1;            // table point
    const int h = g & 1;             // K-half handled by this lane
    if (j > TABLE_M) return;

    const float t  = (float)j * (1.0f / TABLE_M);
    const int   k0 = h * (K_MODES / 2);
    float re = 0.0f, im = 0.0f;

#pragma unroll 8
    for (int k = k0; k < k0 + K_MODES / 2; ++k) {
        const float r  = sW[k] * t;
        const float s  = __builtin_amdgcn_sinf(r);
        const float c  = __builtin_amdgcn_cosf(r);
        const float e  = __builtin_amdgcn_exp2f(sE[k] * t);
        const float ge = sG[k] * e;
        re = fmaf(ge, c, re);
        im = fmaf(ge, s, im);
    }

    // combine the two K-halves (adjacent lanes)
    re += __shfl_xor(re, 1);
    im += __shfl_xor(im, 1);
    if (h == 0) table[j] = make_float2(re, im);
}

// ---------- Kernel B: LDS-staged table, linear interp, 4 points/thread --------
// R2 changes: (1) tg load issued BEFORE staging so its ~900-cycle HBM latency
// hides under the table copy; (2) staging via global_load_lds (16B) removes the
// VGPR round-trip + 8 ds_write_b128/thread. Layout is linear LDS, wave-uniform
// base + lane*16 -- exactly the pattern the instruction requires.
__global__ __launch_bounds__(256) void interp_lds_kernel(
    const float* __restrict__ tg,       // [T], values in [0,1)
    const float2* __restrict__ table,   // [TABLE_M + 1] in global (from kernel A)
    float* __restrict__ out,            // planar: [0..T-1]=re, [T..2T-1]=im
    int T,
    int out_floats)
{
    __shared__ __align__(16) float2 sTab[TABLE_M + 2];

    const int tid  = threadIdx.x;
    const int lane = tid & 63;
    const int wid  = tid >> 6;          // 4 waves per block

    const int i4 = blockIdx.x * blockDim.x + tid;  // group of 4
    const int i  = i4 * 4;
    const bool fast = (i + 3 < T) && (T + i + 3 < out_floats);

    // (1) issue the tg load first -- independent of LDS, overlaps staging
    float4 t4 = make_float4(0.f, 0.f, 0.f, 0.f);
    if (fast) t4 = *(const float4*)(tg + i);

    // (2) async stage: 2048 float4 = 32 KB, 8 iterations of 256 lanes
    {
        const float4* __restrict__ src4 = (const float4*)table;
#pragma unroll
        for (int itr = 0; itr < 8; ++itr) {
            const int jb = itr * 256 + wid * 64;            // wave-uniform
            async_copy16(src4 + jb + lane, (char*)sTab + (size_t)jb * 16);
        }
        if (tid == 0) sTab[TABLE_M] = table[TABLE_M];       // guard entry
    }
    __syncthreads();   // drains vmcnt (incl. global_load_lds) + lgkmcnt

    if (i >= T) return;

    float4 re4, im4;

    if (fast) {
        const float* tv = (const float*)&t4;
        float* rp = (float*)&re4;
        float* ip = (float*)&im4;
#pragma unroll
        for (int c = 0; c < 4; ++c) {
            float u = tv[c] * (float)TABLE_M;
            u = fminf(fmaxf(u, 0.0f), (float)TABLE_M - 0.0001f);
            const int   idx = (int)u;
            const float f   = u - (float)idx;
            const float2 a = sTab[idx];
            const float2 b = sTab[idx + 1];
            rp[c] = fmaf(b.x - a.x, f, a.x);
            ip[c] = fmaf(b.y - a.y, f, a.y);
        }
        *(float4*)(out + i)     = re4;
        *(float4*)(out + T + i) = im4;
    } else {
        // tail / defensive scalar path
        for (int c = 0; c < 4 && i + c < T; ++c) {
            float u = tg[i + c] * (float)TABLE_M;
            u = fminf(fmaxf(u, 0.0f), (float)TABLE_M - 0.0001f);
            const int   idx = (int)u;
            const float f   = u - (float)idx;
            const float2 a = sTab[idx];
            const float2 b = sTab[idx + 1];
            if (i + c < out_floats)     out[i + c]     = fmaf(b.x - a.x, f, a.x);
            if (T + i + c < out_floats) out[T + i + c] = fmaf(b.y - a.y, f, a.y);
        }
    }
}

// ---------- Fallback: proven direct kernel (R4) if d_ws is too small ----------
__global__ __launch_bounds__(256) void propag_direct_kernel(
    const float* __restrict__ params,
    const float* __restrict__ tg,
    float* __restrict__ out,
    int T,
    int out_floats)
{
    __shared__ float sG[K_MODES];
    __shared__ float sW[K_MODES];
    __shared__ float sE[K_MODES];

    const int tid = threadIdx.x;
    if (tid < K_MODES) {
        sG[tid] = params[tid];
        sW[tid] = params[K_MODES + tid]     * 0.15915494309189535f;
        sE[tid] = params[2 * K_MODES + tid] * (-1.4426950408889634f);
    }
    __syncthreads();

    const int i = blockIdx.x * blockDim.x + tid;
    if (i >= T) return;

    const float t = tg[i];
    float re = 0.0f, im = 0.0f;

#pragma unroll 8
    for (int k = 0; k < K_MODES; ++k) {
        const float r  = sW[k] * t;
        const float s  = __builtin_amdgcn_sinf(r);
        const float c  = __builtin_amdgcn_cosf(r);
        const float e  = __builtin_amdgcn_exp2f(sE[k] * t);
        const float ge = sG[k] * e;
        re = fmaf(ge, c, re);
        im = fmaf(ge, s, im);
    }

    if (i < out_floats)     out[i]     = re;
    if (T + i < out_floats) out[T + i] = im;
}

extern "C" void kernel_launch(void* const* d_in, const int* in_sizes, int n_in,
                              void* d_out, int out_size, void* d_ws, size_t ws_size,
                              hipStream_t stream) {
    // Resolve inputs by element count: parameters has exactly 3*128 = 384.
    int ip = 0, it = 1;
    if (in_sizes[0] != 3 * K_MODES) { ip = 1; it = 0; }
    const float* params = (const float*)d_in[ip];
    const float* tg     = (const float*)d_in[it];
    float* out          = (float*)d_out;
    const int T = in_sizes[it];

    const size_t table_bytes = (size_t)(TABLE_M + 2) * sizeof(float2);
    const int block = 256;

    if (ws_size >= table_bytes && d_ws != nullptr) {
        float2* table = (float2*)d_ws;
        const int nthreadA = 2 * (TABLE_M + 1);           // 2 lanes per point
        const int gridA = (nthreadA + block - 1) / block;
        build_table_kernel<<<gridA, block, 0, stream>>>(params, table);

        const int n4 = (T + 3) / 4;
        const int gridB = (n4 + block - 1) / block;
        interp_lds_kernel<<<gridB, block, 0, stream>>>(tg, table, out, T, out_size);
    } else {
        const int grid = (T + block - 1) / block;
        propag_direct_kernel<<<grid, block, 0, stream>>>(params, tg, out, T, out_size);
    }
}